// Round 16
// baseline (15.543 us; speedup 1.0000x reference)
//
#include <hip/hip_runtime.h>
#include <hip/hip_bf16.h>
#include <math.h>

#define NBINS   1024
#define NPART   1024    // partial slabs: 256 blocks x 4 waves, each writes its own
#define PPC     32      // partials per reduce-thread-group (NPART/32)
#define LSTRIDE 136     // ushorts per bin-row: 272B, 16B-aligned; cols 128..135 pad

typedef __attribute__((ext_vector_type(8)))  short short8;   // 8 bf16 = 4 VGPR
typedef __attribute__((ext_vector_type(16))) float f32x16;   // MFMA 32x32 acc

// R15 minus the wave-merge tail: each wave stores its OWN 4KB partial slab
// straight from MFMA registers (all 256 lanes parallel; 3 barriers and the
// 2-stage LDS tree deleted). Partials 1MB->4MB; reduce PPC 8->32 (L2/L3 reads).

__device__ __forceinline__ void make_trees(const float v[10], float valid,
                                           float hi[32], float lo[32])
{
    {
        float t2[2], t4[4], t8[8], t16[16];
        t2[0] = valid * (1.0f - v[0]); t2[1] = valid * v[0];
        #pragma unroll
        for (int k = 0; k < 4; ++k)  t4[k]  = t2[k >> 1]  * ((k & 1) ? v[1] : 1.0f - v[1]);
        #pragma unroll
        for (int k = 0; k < 8; ++k)  t8[k]  = t4[k >> 1]  * ((k & 1) ? v[2] : 1.0f - v[2]);
        #pragma unroll
        for (int k = 0; k < 16; ++k) t16[k] = t8[k >> 1]  * ((k & 1) ? v[3] : 1.0f - v[3]);
        #pragma unroll
        for (int k = 0; k < 32; ++k) hi[k]  = t16[k >> 1] * ((k & 1) ? v[4] : 1.0f - v[4]);
    }
    {
        float t2[2], t4[4], t8[8], t16[16];
        t2[0] = 1.0f - v[5]; t2[1] = v[5];
        #pragma unroll
        for (int k = 0; k < 4; ++k)  t4[k]  = t2[k >> 1]  * ((k & 1) ? v[6] : 1.0f - v[6]);
        #pragma unroll
        for (int k = 0; k < 8; ++k)  t8[k]  = t4[k >> 1]  * ((k & 1) ? v[7] : 1.0f - v[7]);
        #pragma unroll
        for (int k = 0; k < 16; ++k) t16[k] = t8[k >> 1]  * ((k & 1) ? v[8] : 1.0f - v[8]);
        #pragma unroll
        for (int k = 0; k < 32; ++k) lo[k]  = t16[k >> 1] * ((k & 1) ? v[9] : 1.0f - v[9]);
    }
}

__device__ __forceinline__ uint pack2(float a, float b)
{
    __hip_bfloat16 ba = __float2bfloat16(a);
    __hip_bfloat16 bb = __float2bfloat16(b);
    return (uint)(*(const ushort*)&ba) | ((uint)(*(const ushort*)&bb) << 16);
}

__global__ __launch_bounds__(256, 2) void hist_kernel(const float* __restrict__ act,
                                                      float* __restrict__ gC,
                                                      float* __restrict__ out,
                                                      int rows)
{
    __shared__ ushort Phi_u[4][32][LSTRIDE];   // 34KB
    __shared__ ushort Plo_u[4][32][LSTRIDE];   // 34KB (68KB total)

    const int tid  = threadIdx.x;
    const int wav  = tid >> 6;       // 0..3
    const int lane = tid & 63;

    // re-init out each call; kernel boundary orders this before reduce's atomics
    if (blockIdx.x == 0 && tid == 0) out[0] = 0.0f;

    const int r0 = blockIdx.x * 512 + tid;     // batch 0 row
    const int r1 = r0 + 256;                   // batch 1 row

    float v0[10], v1[10];
    float valid0 = 1.0f, valid1 = 1.0f;
    if (r0 < rows) {
        const float2* a2 = (const float2*)(act + (size_t)r0 * 10);
        #pragma unroll
        for (int k = 0; k < 5; ++k) { float2 t = a2[k]; v0[2*k] = t.x; v0[2*k+1] = t.y; }
    } else {
        valid0 = 0.0f;
        #pragma unroll
        for (int k = 0; k < 10; ++k) v0[k] = 0.0f;
    }
    if (r1 < rows) {
        const float2* a2 = (const float2*)(act + (size_t)r1 * 10);
        #pragma unroll
        for (int k = 0; k < 5; ++k) { float2 t = a2[k]; v1[2*k] = t.x; v1[2*k+1] = t.y; }
    } else {
        valid1 = 0.0f;
        #pragma unroll
        for (int k = 0; k < 10; ++k) v1[k] = 0.0f;
    }

    // Both trees (f32), then pack batch-pairs and stage once.
    float hi0[32], lo0[32], hi1[32], lo1[32];
    make_trees(v0, valid0, hi0, lo0);
    make_trees(v1, valid1, hi1, lo1);

    // ushort2{b0,b1} at [q][2*lane]: dword banks (68q+lane)%32 -> 2/bank = free.
    #pragma unroll
    for (int q = 0; q < 32; ++q) {
        *(uint*)&Phi_u[wav][q][2 * lane] = pack2(hi0[q], hi1[q]);
        *(uint*)&Plo_u[wav][q][2 * lane] = pack2(lo0[q], lo1[q]);
    }

    __syncthreads();

    // C(32x32) += Phi^T * Plo over K=128 interleaved rows, 8 MFMAs.
    const int m = lane & 31;
    const int h = lane >> 5;             // 0 or 1

    f32x16 acc = {};
    #pragma unroll
    for (int t = 0; t < 8; ++t) {
        const short8 a = *(const short8*)&Phi_u[wav][m][16 * t + 8 * h];  // 16B aligned
        const short8 b = *(const short8*)&Plo_u[wav][m][16 * t + 8 * h];
        acc = __builtin_amdgcn_mfma_f32_32x32x16_bf16(a, b, acc, 0, 0, 0);
    }

    // No merge: each wave stores its own 4KB slab straight from registers.
    // Per instruction: 64 lanes x 4B = 256B contiguous, all 4 waves parallel.
    float* dst = gC + ((size_t)blockIdx.x * 4 + wav) * NBINS;
    #pragma unroll
    for (int r = 0; r < 16; ++r)
        dst[r * 64 + lane] = acc[r];
}

// Fused reduce + finalize, bins-complete-per-block (R12-verified geometry).
// 128 blocks x 256 threads; block owns 8 bins; thread (g,b) sums partials
// g+32j (j=0..31) with 4 independent accumulators (anti-R9 MLP).
__global__ __launch_bounds__(256) void reduce_kernel(const float* __restrict__ gC,
                                                     float* __restrict__ out,
                                                     float invB)
{
    __shared__ float red[32][8];     // [partial-group][bin-local]
    const int tid = threadIdx.x;
    const int g   = tid >> 3;        // 0..31
    const int b   = tid & 7;         // 0..7
    const int bin = blockIdx.x * 8 + b;

    const float* p = gC + (size_t)g * NBINS + bin;   // +32*NBINS per step
    float a0 = 0.f, a1 = 0.f, a2 = 0.f, a3 = 0.f;
    #pragma unroll
    for (int j = 0; j < PPC; j += 4) {
        a0 += p[(size_t)(j + 0) * 32 * NBINS];
        a1 += p[(size_t)(j + 1) * 32 * NBINS];
        a2 += p[(size_t)(j + 2) * 32 * NBINS];
        a3 += p[(size_t)(j + 3) * 32 * NBINS];
    }
    red[g][b] = (a0 + a1) + (a2 + a3);
    __syncthreads();

    if (tid < 8) {
        float t = 0.0f;
        #pragma unroll
        for (int k = 0; k < 32; ++k) t += red[k][tid];
        const float pa = t * invB;
        float e = pa * log2f(fmaxf(pa, 1e-12f));   // sum p*log2(clip(p)) = -joint_h
        e += __shfl_down(e, 4);
        e += __shfl_down(e, 2);
        e += __shfl_down(e, 1);
        if (tid == 0) atomicAdd(out, e);           // 128 adds total, device scope
    }
}

extern "C" void kernel_launch(void* const* d_in, const int* in_sizes, int n_in,
                              void* d_out, int out_size, void* d_ws, size_t ws_size,
                              hipStream_t stream)
{
    const float* act = (const float*)d_in[0];
    const int rows = in_sizes[0] / 10;        // B = 131072 = 256 * 512
    float* gC  = (float*)d_ws;                // NPART x NBINS partials (4MB)
    float* out = (float*)d_out;

    hist_kernel<<<256, 256, 0, stream>>>(act, gC, out, rows);
    reduce_kernel<<<128, 256, 0, stream>>>(gC, out, 1.0f / (float)rows);
}

// Round 17
// 13.454 us; speedup vs baseline: 1.1553x; 1.1553x over previous
//
#include <hip/hip_runtime.h>
#include <hip/hip_bf16.h>
#include <math.h>

#define NBINS   1024
#define NPART   256     // hist grid: 256 blocks x 256 threads (4 waves x 128 k-rows)
#define PPC     8       // partials per reduce-thread (NPART/32)
#define LSTRIDE 136     // ushorts per bin-row: 272B, 16B-aligned; cols 128..135 pad

typedef __attribute__((ext_vector_type(8)))  short short8;   // 8 bf16 = 4 VGPR
typedef __attribute__((ext_vector_type(16))) float f32x16;   // MFMA 32x32 acc

// R15 verbatim (verified 13.74us session minimum). R16's merge-removal (+1.8us)
// and R14's thinner blocks (+0.33us) both measured worse; this is the optimum
// of the explored structure space. ~3.5us kernel work + ~10us launch floor.

__device__ __forceinline__ void make_trees(const float v[10], float valid,
                                           float hi[32], float lo[32])
{
    {
        float t2[2], t4[4], t8[8], t16[16];
        t2[0] = valid * (1.0f - v[0]); t2[1] = valid * v[0];
        #pragma unroll
        for (int k = 0; k < 4; ++k)  t4[k]  = t2[k >> 1]  * ((k & 1) ? v[1] : 1.0f - v[1]);
        #pragma unroll
        for (int k = 0; k < 8; ++k)  t8[k]  = t4[k >> 1]  * ((k & 1) ? v[2] : 1.0f - v[2]);
        #pragma unroll
        for (int k = 0; k < 16; ++k) t16[k] = t8[k >> 1]  * ((k & 1) ? v[3] : 1.0f - v[3]);
        #pragma unroll
        for (int k = 0; k < 32; ++k) hi[k]  = t16[k >> 1] * ((k & 1) ? v[4] : 1.0f - v[4]);
    }
    {
        float t2[2], t4[4], t8[8], t16[16];
        t2[0] = 1.0f - v[5]; t2[1] = v[5];
        #pragma unroll
        for (int k = 0; k < 4; ++k)  t4[k]  = t2[k >> 1]  * ((k & 1) ? v[6] : 1.0f - v[6]);
        #pragma unroll
        for (int k = 0; k < 8; ++k)  t8[k]  = t4[k >> 1]  * ((k & 1) ? v[7] : 1.0f - v[7]);
        #pragma unroll
        for (int k = 0; k < 16; ++k) t16[k] = t8[k >> 1]  * ((k & 1) ? v[8] : 1.0f - v[8]);
        #pragma unroll
        for (int k = 0; k < 32; ++k) lo[k]  = t16[k >> 1] * ((k & 1) ? v[9] : 1.0f - v[9]);
    }
}

__device__ __forceinline__ uint pack2(float a, float b)
{
    __hip_bfloat16 ba = __float2bfloat16(a);
    __hip_bfloat16 bb = __float2bfloat16(b);
    return (uint)(*(const ushort*)&ba) | ((uint)(*(const ushort*)&bb) << 16);
}

__global__ __launch_bounds__(256, 2) void hist_kernel(const float* __restrict__ act,
                                                      float* __restrict__ gC,
                                                      float* __restrict__ out,
                                                      int rows)
{
    __shared__ ushort Phi_u[4][32][LSTRIDE];   // 34KB
    __shared__ ushort Plo_u[4][32][LSTRIDE];   // 34KB
    __shared__ float  C_buf[2][NBINS];         // 8KB merge buffer (76KB total)

    const int tid  = threadIdx.x;
    const int wav  = tid >> 6;       // 0..3
    const int lane = tid & 63;

    // re-init out each call; kernel boundary orders this before reduce's atomics
    if (blockIdx.x == 0 && tid == 0) out[0] = 0.0f;

    const int r0 = blockIdx.x * 512 + tid;     // batch 0 row
    const int r1 = r0 + 256;                   // batch 1 row

    float v0[10], v1[10];
    float valid0 = 1.0f, valid1 = 1.0f;
    if (r0 < rows) {
        const float2* a2 = (const float2*)(act + (size_t)r0 * 10);
        #pragma unroll
        for (int k = 0; k < 5; ++k) { float2 t = a2[k]; v0[2*k] = t.x; v0[2*k+1] = t.y; }
    } else {
        valid0 = 0.0f;
        #pragma unroll
        for (int k = 0; k < 10; ++k) v0[k] = 0.0f;
    }
    if (r1 < rows) {
        const float2* a2 = (const float2*)(act + (size_t)r1 * 10);
        #pragma unroll
        for (int k = 0; k < 5; ++k) { float2 t = a2[k]; v1[2*k] = t.x; v1[2*k+1] = t.y; }
    } else {
        valid1 = 0.0f;
        #pragma unroll
        for (int k = 0; k < 10; ++k) v1[k] = 0.0f;
    }

    // Both trees (f32), then pack batch-pairs and stage once.
    float hi0[32], lo0[32], hi1[32], lo1[32];
    make_trees(v0, valid0, hi0, lo0);
    make_trees(v1, valid1, hi1, lo1);

    // ushort2{b0,b1} at [q][2*lane]: dword banks (68q+lane)%32 -> 2/bank = free.
    #pragma unroll
    for (int q = 0; q < 32; ++q) {
        *(uint*)&Phi_u[wav][q][2 * lane] = pack2(hi0[q], hi1[q]);
        *(uint*)&Plo_u[wav][q][2 * lane] = pack2(lo0[q], lo1[q]);
    }

    __syncthreads();

    // C(32x32) += Phi^T * Plo over K=128 interleaved rows, 8 MFMAs.
    const int m = lane & 31;
    const int h = lane >> 5;             // 0 or 1

    f32x16 acc = {};
    #pragma unroll
    for (int t = 0; t < 8; ++t) {
        const short8 a = *(const short8*)&Phi_u[wav][m][16 * t + 8 * h];  // 16B aligned
        const short8 b = *(const short8*)&Plo_u[wav][m][16 * t + 8 * h];
        acc = __builtin_amdgcn_mfma_f32_32x32x16_bf16(a, b, acc, 0, 0, 0);
    }

    // 2-stage merge tree (no atomics): {1->0, 3->2} then {2->0}; wave0 stores
    // directly from registers. Banks = lane%32 -> 2/bank = free.
    if (wav == 1 || wav == 3) {
        #pragma unroll
        for (int r = 0; r < 16; ++r)
            C_buf[wav >> 1][r * 64 + lane] = acc[r];
    }
    __syncthreads();
    if (wav == 0 || wav == 2) {
        #pragma unroll
        for (int r = 0; r < 16; ++r)
            acc[r] += C_buf[wav >> 1][r * 64 + lane];
    }
    __syncthreads();
    if (wav == 2) {
        #pragma unroll
        for (int r = 0; r < 16; ++r)
            C_buf[0][r * 64 + lane] = acc[r];
    }
    __syncthreads();
    if (wav == 0) {
        float* dst = gC + (size_t)blockIdx.x * NBINS;
        #pragma unroll
        for (int r = 0; r < 16; ++r)
            dst[r * 64 + lane] = acc[r] + C_buf[0][r * 64 + lane];  // 256B coalesced
    }
}

// Fused reduce + finalize, bins-complete-per-block (R12-verified geometry).
// 128 blocks x 256 threads; block owns 8 bins; thread (g,b) sums partials
// g+32j (j=0..7) with 4 independent accumulators.
__global__ __launch_bounds__(256) void reduce_kernel(const float* __restrict__ gC,
                                                     float* __restrict__ out,
                                                     float invB)
{
    __shared__ float red[32][8];     // [partial-group][bin-local]
    const int tid = threadIdx.x;
    const int g   = tid >> 3;        // 0..31
    const int b   = tid & 7;         // 0..7
    const int bin = blockIdx.x * 8 + b;

    const float* p = gC + (size_t)g * NBINS + bin;   // +32*NBINS per step
    float a0 = 0.f, a1 = 0.f, a2 = 0.f, a3 = 0.f;
    #pragma unroll
    for (int j = 0; j < PPC; j += 4) {
        a0 += p[(size_t)(j + 0) * 32 * NBINS];
        a1 += p[(size_t)(j + 1) * 32 * NBINS];
        a2 += p[(size_t)(j + 2) * 32 * NBINS];
        a3 += p[(size_t)(j + 3) * 32 * NBINS];
    }
    red[g][b] = (a0 + a1) + (a2 + a3);
    __syncthreads();

    if (tid < 8) {
        float t = 0.0f;
        #pragma unroll
        for (int k = 0; k < 32; ++k) t += red[k][tid];
        const float pa = t * invB;
        float e = pa * log2f(fmaxf(pa, 1e-12f));   // sum p*log2(clip(p)) = -joint_h
        e += __shfl_down(e, 4);
        e += __shfl_down(e, 2);
        e += __shfl_down(e, 1);
        if (tid == 0) atomicAdd(out, e);           // 128 adds total, device scope
    }
}

extern "C" void kernel_launch(void* const* d_in, const int* in_sizes, int n_in,
                              void* d_out, int out_size, void* d_ws, size_t ws_size,
                              hipStream_t stream)
{
    const float* act = (const float*)d_in[0];
    const int rows = in_sizes[0] / 10;        // B = 131072 = 256 * 512
    float* gC  = (float*)d_ws;                // NPART x NBINS partials (1MB)
    float* out = (float*)d_out;

    hist_kernel<<<NPART, 256, 0, stream>>>(act, gC, out, rows);
    reduce_kernel<<<128, 256, 0, stream>>>(gC, out, 1.0f / (float)rows);
}